// Round 7
// baseline (5472.554 us; speedup 1.0000x reference)
//
#include <hip/hip_runtime.h>
#include <math.h>

#define NANG 720
#define NDET 512
#define KPTS (NANG*NDET)        // 368640
#define G 1024
#define GG (G*G)
#define ALPHA_F 14.04f
#define NITER_DCOMP 10
#define WW 512

#define CAP 4096                 // max points per scatter chunk
#define PAIR_CAP 1474624         // >= hard worst case 4*KPTS = 1474560
#define NSCATTER_BLOCKS 1536     // >= 1024 + 4*KPTS/CAP = 1384

// ---------------- workspace layout (byte offsets) --------------------------
#define O_TW512   0UL            // 512 double2
#define O_TW1024  8192UL         // 1024 double2
#define O_DPOD    24576UL        // 512 f32
#define O_CNT     32768UL        // 1024 int
#define O_FILL    36864UL        // 1024 int
#define O_START   40960UL        // 1025 int
#define O_NCH     46080UL        // 1 int
#define O_CHUNK   49152UL        // 2048 int4 (32KB)
#define O_REC     131072UL       // KPTS * 64B = 23.6MB   (reused as W1T later)
#define O_PAIRS   (O_REC   + (size_t)KPTS*64)       // PAIR_CAP int = 5.9MB
#define O_WDC     (O_PAIRS + (size_t)PAIR_CAP*4)    // K f32
#define O_KD      (O_WDC   + (size_t)KPTS*4)        // K float2
#define O_GR      (O_KD    + (size_t)KPTS*8)        // GG f32
#define O_GC      (O_GR    + (size_t)GG*4)          // GG float2
// end ~44.5MB

struct __align__(16) PointRec {
  float wy[6];
  float wx[6];
  int   iy0, ix0;
  int   pad0, pad1;   // 64B total
};

// ---------------- modified Bessel I0 (Abramowitz-Stegun) -------------------
__device__ __forceinline__ float i0f(float x){
  float ax = fabsf(x);
  if (ax < 3.75f){
    float t = ax*(1.0f/3.75f); t *= t;
    return 1.0f + t*(3.5156229f + t*(3.0899424f + t*(1.2067492f +
           t*(0.2659732f + t*(0.0360768f + t*0.0045813f)))));
  } else {
    float t = 3.75f/ax;
    float p = 0.39894228f + t*(0.01328592f + t*(0.00225319f + t*(-0.00157565f +
              t*(0.00916281f + t*(-0.02057706f + t*(0.02635537f +
              t*(-0.01647633f + t*0.00392377f)))))));
    return expf(ax)*rsqrtf(ax)*p;
  }
}

// ---------------- tables ---------------------------------------------------
__global__ __launch_bounds__(256) void gen_tables(double2* tw512, double2* tw1024, float* dpod){
  int i = blockIdx.x*blockDim.x + threadIdx.x;
  if (i < 512){
    double ang = -2.0*M_PI*(double)i/512.0;
    tw512[i] = make_double2(cos(ang), sin(ang));
  }
  if (i < 1024){
    double ang = 2.0*M_PI*(double)i/1024.0;
    tw1024[i] = make_double2(cos(ang), sin(ang));
  }
  if (i < 512){
    float n  = (float)i - 256.0f;
    float xi = n * (1.0f/(float)G);
    float a  = (float)M_PI * 6.0f * xi;
    float t  = a*a - ALPHA_F*ALPHA_F;
    float z  = sqrtf(fabsf(t));
    float kbft;
    if (t < 0.0f) kbft = sinhf(z) / fmaxf(z, 1e-12f);
    else          kbft = (z < 1e-12f) ? 1.0f : sinf(z)/z;
    kbft *= 6.0f / i0f(ALPHA_F);
    dpod[i] = 1.0f / kbft;
  }
}

// ---------------- KB records per point -------------------------------------
__global__ __launch_bounds__(256) void precompute_kb(const float* __restrict__ ktraj,
    PointRec* __restrict__ rec, float* __restrict__ wdc){
  int k = blockIdx.x*blockDim.x + threadIdx.x;
  if (k >= KPTS) return;
  const float gfac = (float)((double)G/(2.0*M_PI));
  const float inv_i0a = 1.0f / i0f(ALPHA_F);
  PointRec r;
  #pragma unroll
  for (int dim = 0; dim < 2; ++dim){
    float om = ktraj[(size_t)dim*KPTS + k];
    float gx = om * gfac;
    int k0 = (int)floorf(gx);
    #pragma unroll
    for (int j = 0; j < 6; ++j){
      int idx = k0 + (j - 2);
      float d = gx - (float)idx;
      float u = (2.0f*d)*(1.0f/6.0f);
      float t = 1.0f - u*u;
      float w = 0.0f;
      if (t > 0.0f) w = i0f(ALPHA_F * sqrtf(fmaxf(t, 1e-20f))) * inv_i0a;
      if (dim == 0) r.wy[j] = w; else r.wx[j] = w;
    }
    int i0v = (k0 - 2 + 2048) & (G-1);
    if (dim == 0) r.iy0 = i0v; else r.ix0 = i0v;
  }
  r.pad0 = 0; r.pad1 = 0;
  rec[k] = r;
  wdc[k] = 1.0f;
}

// ---------------- tile list build ------------------------------------------
__device__ __forceinline__ int tiles_of(int iy0, int ix0, int* tl){
  int ty0 = iy0>>5, ty1 = ((iy0+5)&(G-1))>>5;
  int tx0 = ix0>>5, tx1 = ((ix0+5)&(G-1))>>5;
  int n = 0;
  tl[n++] = ty0*32+tx0;
  if (tx1!=tx0) tl[n++] = ty0*32+tx1;
  if (ty1!=ty0){
    tl[n++] = ty1*32+tx0;
    if (tx1!=tx0) tl[n++] = ty1*32+tx1;
  }
  return n;
}

__global__ __launch_bounds__(256) void count_tiles(const PointRec* __restrict__ rec,
    int* __restrict__ cnt){
  int k = blockIdx.x*blockDim.x + threadIdx.x;
  if (k >= KPTS) return;
  int tl[4];
  int n = tiles_of(rec[k].iy0, rec[k].ix0, tl);
  for (int i=0;i<n;i++) atomicAdd(&cnt[tl[i]], 1);
}

__global__ __launch_bounds__(1024) void scan_build(const int* __restrict__ cnt,
    int* __restrict__ tileStart, int4* __restrict__ chunkTbl, int* __restrict__ nChunks){
  __shared__ int s[1024];
  int t = threadIdx.x;
  int c = cnt[t];
  s[t] = c; __syncthreads();
  for (int off=1; off<1024; off<<=1){
    int v = (t>=off) ? s[t-off] : 0;
    __syncthreads();
    s[t] += v;
    __syncthreads();
  }
  int excl = s[t] - c;
  tileStart[t] = excl;
  if (t==1023) tileStart[1024] = s[1023];
  int nch = (c + CAP - 1)/CAP;
  __syncthreads();
  s[t] = nch; __syncthreads();
  for (int off=1; off<1024; off<<=1){
    int v = (t>=off) ? s[t-off] : 0;
    __syncthreads();
    s[t] += v;
    __syncthreads();
  }
  int cbase = s[t] - nch;
  for (int i=0;i<nch;i++)
    chunkTbl[cbase+i] = make_int4(t, excl + i*CAP, min(CAP, c - i*CAP), 0);
  if (t==1023) *nChunks = s[1023];
}

__global__ __launch_bounds__(256) void fill_pairs(const PointRec* __restrict__ rec,
    const int* __restrict__ tileStart, int* __restrict__ fill, int* __restrict__ pairs){
  int k = blockIdx.x*blockDim.x + threadIdx.x;
  if (k >= KPTS) return;
  int tl[4];
  int n = tiles_of(rec[k].iy0, rec[k].ix0, tl);
  for (int i=0;i<n;i++){
    int t = tl[i];
    int pos = atomicAdd(&fill[t], 1);
    pairs[tileStart[t] + pos] = k;
  }
}

// ---------------- 512-pt row DFT with fftshifts (f64 accum) ----------------
__global__ __launch_bounds__(256) void rowfft(const float* __restrict__ sino,
    const double2* __restrict__ tw512g, float2* __restrict__ kd){
  __shared__ float   srow[NDET];
  __shared__ double2 tw[NDET];
  int a = blockIdx.x;
  for (int i = threadIdx.x; i < NDET; i += blockDim.x){
    srow[i] = sino[(size_t)a*NDET + i];
    tw[i]   = tw512g[i];
  }
  __syncthreads();
  int k0 = threadIdx.x, k1 = threadIdx.x + 256;
  int kp0 = (k0 + 256) & 511, kp1 = (k1 + 256) & 511;
  double ar0=0, ai0=0, ar1=0, ai1=0;
  for (int n = 0; n < NDET; ++n){
    float s = srow[(n + 256) & 511];
    double2 t0 = tw[(n*kp0) & 511];
    double2 t1 = tw[(n*kp1) & 511];
    ar0 += s*t0.x; ai0 += s*t0.y;
    ar1 += s*t1.x; ai1 += s*t1.y;
  }
  kd[(size_t)a*NDET + k0] = make_float2((float)ar0, (float)ai0);
  kd[(size_t)a*NDET + k1] = make_float2((float)ar1, (float)ai1);
}

// ---------------- owner-cell scatter (gather form): real -------------------
// Each thread owns 4 cells (row t>>5 + 8s, col t&31). Points staged to LDS in
// batches of 256; branchless accumulation via zero-padded weight rows 6,7.
__global__ __launch_bounds__(256) void scatter_real_g(
    const int4* __restrict__ chunkTbl, const int* __restrict__ nChunks,
    const int* __restrict__ pairs, const PointRec* __restrict__ rec,
    const float* __restrict__ wdc, float* __restrict__ grid){
  __shared__ float s_wy[8][257];
  __shared__ float s_wx[8][257];
  __shared__ int   s_iy[256], s_ix[256];
  int b = blockIdx.x;
  if (b >= *nChunks) return;
  int4 ch = chunkTbl[b];
  int tyc = (ch.x>>5)<<5, txc = (ch.x&31)<<5;
  int t = threadIdx.x;
  int cx  = txc + (t & 31);
  int cy0 = tyc + (t >> 5);
  // zero pad rows 6,7 once
  for (int i = t; i < 257; i += 256){
    s_wy[6][i]=0.f; s_wy[7][i]=0.f; s_wx[6][i]=0.f; s_wx[7][i]=0.f;
  }
  float acc0=0.f, acc1=0.f, acc2=0.f, acc3=0.f;
  for (int base = 0; base < ch.z; base += 256){
    int n = min(256, ch.z - base);
    __syncthreads();
    if (t < n){
      int k = pairs[ch.y + base + t];
      PointRec r = rec[k];
      float val = wdc[k];
      #pragma unroll
      for (int j = 0; j < 6; ++j){ s_wy[j][t] = r.wy[j]; s_wx[j][t] = r.wx[j]*val; }
      s_iy[t] = r.iy0; s_ix[t] = r.ix0;
    }
    __syncthreads();
    for (int p = 0; p < n; ++p){
      int ix0 = s_ix[p], iy0 = s_iy[p];
      int dx  = (cx - ix0) & (G-1);
      float wxv = s_wx[min(dx,7)][p];
      int dy0 = (cy0 - iy0) & (G-1);
      int dy1 = (dy0 + 8)  & (G-1);
      int dy2 = (dy0 + 16) & (G-1);
      int dy3 = (dy0 + 24) & (G-1);
      acc0 = fmaf(s_wy[min(dy0,7)][p], wxv, acc0);
      acc1 = fmaf(s_wy[min(dy1,7)][p], wxv, acc1);
      acc2 = fmaf(s_wy[min(dy2,7)][p], wxv, acc2);
      acc3 = fmaf(s_wy[min(dy3,7)][p], wxv, acc3);
    }
  }
  size_t rowb = ((size_t)cy0 << 10) + cx;
  if (acc0 != 0.f) atomicAdd(&grid[rowb],           acc0);
  if (acc1 != 0.f) atomicAdd(&grid[rowb + (8<<10)], acc1);
  if (acc2 != 0.f) atomicAdd(&grid[rowb + (16<<10)],acc2);
  if (acc3 != 0.f) atomicAdd(&grid[rowb + (24<<10)],acc3);
}

// ---------------- owner-cell scatter (gather form): complex ----------------
__global__ __launch_bounds__(256) void scatter_cplx_g(
    const int4* __restrict__ chunkTbl, const int* __restrict__ nChunks,
    const int* __restrict__ pairs, const PointRec* __restrict__ rec,
    const float2* __restrict__ kd, const float* __restrict__ wdc,
    float* __restrict__ gridc){
  __shared__ float s_wy [8][257];
  __shared__ float s_wxr[8][257];
  __shared__ float s_wxi[8][257];
  __shared__ int   s_iy[256], s_ix[256];
  int b = blockIdx.x;
  if (b >= *nChunks) return;
  int4 ch = chunkTbl[b];
  int tyc = (ch.x>>5)<<5, txc = (ch.x&31)<<5;
  int t = threadIdx.x;
  int cx  = txc + (t & 31);
  int cy0 = tyc + (t >> 5);
  for (int i = t; i < 257; i += 256){
    s_wy[6][i]=0.f; s_wy[7][i]=0.f;
    s_wxr[6][i]=0.f; s_wxr[7][i]=0.f;
    s_wxi[6][i]=0.f; s_wxi[7][i]=0.f;
  }
  float ar0=0.f, ar1=0.f, ar2=0.f, ar3=0.f;
  float ai0=0.f, ai1=0.f, ai2=0.f, ai3=0.f;
  for (int base = 0; base < ch.z; base += 256){
    int n = min(256, ch.z - base);
    __syncthreads();
    if (t < n){
      int k = pairs[ch.y + base + t];
      PointRec r = rec[k];
      float2 kv = kd[k];
      float dc = wdc[k];
      float vr = kv.x*dc, vi = kv.y*dc;
      #pragma unroll
      for (int j = 0; j < 6; ++j){
        s_wy [j][t] = r.wy[j];
        s_wxr[j][t] = r.wx[j]*vr;
        s_wxi[j][t] = r.wx[j]*vi;
      }
      s_iy[t] = r.iy0; s_ix[t] = r.ix0;
    }
    __syncthreads();
    for (int p = 0; p < n; ++p){
      int ix0 = s_ix[p], iy0 = s_iy[p];
      int dx  = (cx - ix0) & (G-1);
      int dxc = min(dx,7);
      float wr = s_wxr[dxc][p];
      float wi = s_wxi[dxc][p];
      int dy0 = (cy0 - iy0) & (G-1);
      int dy1 = (dy0 + 8)  & (G-1);
      int dy2 = (dy0 + 16) & (G-1);
      int dy3 = (dy0 + 24) & (G-1);
      float w0 = s_wy[min(dy0,7)][p];
      float w1 = s_wy[min(dy1,7)][p];
      float w2 = s_wy[min(dy2,7)][p];
      float w3 = s_wy[min(dy3,7)][p];
      ar0 = fmaf(w0, wr, ar0);  ai0 = fmaf(w0, wi, ai0);
      ar1 = fmaf(w1, wr, ar1);  ai1 = fmaf(w1, wi, ai1);
      ar2 = fmaf(w2, wr, ar2);  ai2 = fmaf(w2, wi, ai2);
      ar3 = fmaf(w3, wr, ar3);  ai3 = fmaf(w3, wi, ai3);
    }
  }
  size_t cell = ((size_t)cy0 << 10) + cx;
  if (ar0 != 0.f || ai0 != 0.f){ atomicAdd(&gridc[cell*2],            ar0); atomicAdd(&gridc[cell*2+1],            ai0); }
  if (ar1 != 0.f || ai1 != 0.f){ atomicAdd(&gridc[(cell+(8<<10))*2],  ar1); atomicAdd(&gridc[(cell+(8<<10))*2+1],  ai1); }
  if (ar2 != 0.f || ai2 != 0.f){ atomicAdd(&gridc[(cell+(16<<10))*2], ar2); atomicAdd(&gridc[(cell+(16<<10))*2+1], ai2); }
  if (ar3 != 0.f || ai3 != 0.f){ atomicAdd(&gridc[(cell+(24<<10))*2], ar3); atomicAdd(&gridc[(cell+(24<<10))*2+1], ai3); }
}

// ---------------- gather + divide (dcomp) ----------------------------------
__global__ __launch_bounds__(256) void gather_div(const PointRec* __restrict__ rec,
    const float* __restrict__ grid, float* __restrict__ wdc){
  int k = blockIdx.x*blockDim.x + threadIdx.x;
  if (k >= KPTS) return;
  PointRec r = rec[k];
  float s = 0.f;
  #pragma unroll
  for (int j = 0; j < 6; ++j){
    int rowb = ((r.iy0 + j) & (G-1)) << 10;
    float rs = 0.f;
    #pragma unroll
    for (int i = 0; i < 6; ++i)
      rs += grid[rowb + ((r.ix0 + i) & (G-1))] * r.wx[i];
    s += rs * r.wy[j];
  }
  wdc[k] = wdc[k] / fmaxf(fabsf(s), 1e-12f);
}

// ---------------- IFFT pass 1: rows ----------------------------------------
__global__ __launch_bounds__(256) void ifft_rows(const float2* __restrict__ gridc,
    const double2* __restrict__ tw1024g, float2* __restrict__ W1T){
  __shared__ float2  row[G];
  __shared__ double2 tw[G];
  int r = blockIdx.x;
  for (int i = threadIdx.x; i < G; i += blockDim.x){
    row[i] = gridc[(size_t)r*G + i];
    tw[i]  = tw1024g[i];
  }
  __syncthreads();
  int q0 = threadIdx.x, q1 = threadIdx.x + 256;
  int m0 = (q0 + 768) & (G-1), m1 = (q1 + 768) & (G-1);
  double ar0=0, ai0=0, ar1=0, ai1=0;
  for (int c = 0; c < G; ++c){
    float2 v = row[c];
    double2 t0 = tw[(c*m0) & (G-1)];
    double2 t1 = tw[(c*m1) & (G-1)];
    ar0 += v.x*t0.x - v.y*t0.y;  ai0 += v.x*t0.y + v.y*t0.x;
    ar1 += v.x*t1.x - v.y*t1.y;  ai1 += v.x*t1.y + v.y*t1.x;
  }
  W1T[(size_t)q0*G + r] = make_float2((float)ar0, (float)ai0);
  W1T[(size_t)q1*G + r] = make_float2((float)ar1, (float)ai1);
}

// ---------------- IFFT pass 2: cols + deapod + crop ------------------------
__global__ __launch_bounds__(256) void ifft_cols(const float2* __restrict__ W1T,
    const double2* __restrict__ tw1024g, const float* __restrict__ dpod,
    float* __restrict__ out){
  __shared__ float2  col[G];
  __shared__ double2 tw[G];
  int q = blockIdx.x;
  for (int i = threadIdx.x; i < G; i += blockDim.x){
    col[i] = W1T[(size_t)q*G + i];
    tw[i]  = tw1024g[i];
  }
  __syncthreads();
  float dq = dpod[q];
  int p0 = threadIdx.x, p1 = threadIdx.x + 256;
  int m0 = (p0 + 768) & (G-1), m1 = (p1 + 768) & (G-1);
  double ar0=0, ar1=0;
  for (int r = 0; r < G; ++r){
    float2 v = col[r];
    double2 t0 = tw[(r*m0) & (G-1)];
    double2 t1 = tw[(r*m1) & (G-1)];
    ar0 += v.x*t0.x - v.y*t0.y;
    ar1 += v.x*t1.x - v.y*t1.y;
  }
  out[(size_t)p0*WW + q] = (float)ar0 * (1.0f/1024.0f) * dpod[p0] * dq;
  out[(size_t)p1*WW + q] = (float)ar1 * (1.0f/1024.0f) * dpod[p1] * dq;
}

// ---------------------------------------------------------------------------
extern "C" void kernel_launch(void* const* d_in, const int* in_sizes, int n_in,
                              void* d_out, int out_size, void* d_ws, size_t ws_size,
                              hipStream_t stream){
  const float* sino  = (const float*)d_in[0];
  const float* ktraj = (const float*)d_in[1];
  float* out = (float*)d_out;
  char* ws = (char*)d_ws;

  double2*  tw512   = (double2*) (ws + O_TW512);
  double2*  tw1024  = (double2*) (ws + O_TW1024);
  float*    dpod    = (float*)   (ws + O_DPOD);
  int*      cnt     = (int*)     (ws + O_CNT);
  int*      fill    = (int*)     (ws + O_FILL);
  int*      tstart  = (int*)     (ws + O_START);
  int*      nch     = (int*)     (ws + O_NCH);
  int4*     chunkT  = (int4*)    (ws + O_CHUNK);
  PointRec* rec     = (PointRec*)(ws + O_REC);
  int*      pairs   = (int*)     (ws + O_PAIRS);
  float*    wdc     = (float*)   (ws + O_WDC);
  float2*   kd      = (float2*)  (ws + O_KD);
  float*    gridR   = (float*)   (ws + O_GR);
  float2*   gridC   = (float2*)  (ws + O_GC);
  float2*   W1T     = (float2*)  (ws + O_REC);   // reuse record space (dead by then)

  const int PB = (KPTS + 255)/256;   // 1440

  gen_tables<<<4, 256, 0, stream>>>(tw512, tw1024, dpod);
  precompute_kb<<<PB, 256, 0, stream>>>(ktraj, rec, wdc);
  rowfft<<<NANG, 256, 0, stream>>>(sino, tw512, kd);

  // build tile lists (once per call; reused by all 11 scatters)
  hipMemsetAsync(cnt, 0, 8192, stream);          // cnt + fill (adjacent)
  count_tiles<<<PB, 256, 0, stream>>>(rec, cnt);
  scan_build<<<1, 1024, 0, stream>>>(cnt, tstart, chunkT, nch);
  fill_pairs<<<PB, 256, 0, stream>>>(rec, tstart, fill, pairs);

  for (int it = 0; it < NITER_DCOMP; ++it){
    hipMemsetAsync(gridR, 0, (size_t)GG*sizeof(float), stream);
    scatter_real_g<<<NSCATTER_BLOCKS, 256, 0, stream>>>(chunkT, nch, pairs, rec, wdc, gridR);
    gather_div<<<PB, 256, 0, stream>>>(rec, gridR, wdc);
  }

  hipMemsetAsync(gridC, 0, (size_t)GG*2*sizeof(float), stream);
  scatter_cplx_g<<<NSCATTER_BLOCKS, 256, 0, stream>>>(chunkT, nch, pairs, rec, kd, wdc, (float*)gridC);

  ifft_rows<<<G, 256, 0, stream>>>(gridC, tw1024, W1T);
  ifft_cols<<<WW, 256, 0, stream>>>(W1T, tw1024, dpod, out);
}

// Round 10
// 2965.136 us; speedup vs baseline: 1.8456x; 1.8456x over previous
//
#include <hip/hip_runtime.h>
#include <math.h>

#define NANG 720
#define NDET 512
#define KPTS (NANG*NDET)        // 368640
#define G 1024
#define GG (G*G)
#define ALPHA_F 14.04f
#define NITER_DCOMP 10
#define WW 512

#define CAP 1024                 // max points per scatter chunk (was 4096: DC straggler)
#define PAIR_CAP 1474624         // >= hard worst case 4*KPTS = 1474560
#define NSCATTER_BLOCKS 2464     // >= 1024 + PAIR_CAP/CAP = 2464

// ---------------- workspace layout (byte offsets) --------------------------
#define O_TW512   0UL            // 512 double2
#define O_TW1024  8192UL         // 1024 double2
#define O_DPOD    24576UL        // 512 f32
#define O_CNT     32768UL        // 1024 int
#define O_FILL    36864UL        // 1024 int
#define O_START   40960UL        // 1025 int
#define O_NCH     46080UL        // 1 int
#define O_CHUNK   49152UL        // 4096 int4 (64KB; need <= 2464)
#define O_REC     131072UL       // KPTS * 64B = 23.6MB   (reused as W1T later)
#define O_PAIRS   (O_REC   + (size_t)KPTS*64)       // PAIR_CAP int = 5.9MB
#define O_WDC     (O_PAIRS + (size_t)PAIR_CAP*4)    // K f32
#define O_KD      (O_WDC   + (size_t)KPTS*4)        // K float2
#define O_GR      (O_KD    + (size_t)KPTS*8)        // GG f32
#define O_GC      (O_GR    + (size_t)GG*4)          // GG float2
// end ~44.5MB

struct __align__(16) PointRec {
  float wy[6];
  float wx[6];
  int   iy0, ix0;
  int   pad0, pad1;   // 64B total
};

// ---------------- modified Bessel I0 (Abramowitz-Stegun) -------------------
__device__ __forceinline__ float i0f(float x){
  float ax = fabsf(x);
  if (ax < 3.75f){
    float t = ax*(1.0f/3.75f); t *= t;
    return 1.0f + t*(3.5156229f + t*(3.0899424f + t*(1.2067492f +
           t*(0.2659732f + t*(0.0360768f + t*0.0045813f)))));
  } else {
    float t = 3.75f/ax;
    float p = 0.39894228f + t*(0.01328592f + t*(0.00225319f + t*(-0.00157565f +
              t*(0.00916281f + t*(-0.02057706f + t*(0.02635537f +
              t*(-0.01647633f + t*0.00392377f)))))));
    return expf(ax)*rsqrtf(ax)*p;
  }
}

// ---------------- tables ---------------------------------------------------
__global__ __launch_bounds__(256) void gen_tables(double2* tw512, double2* tw1024, float* dpod){
  int i = blockIdx.x*blockDim.x + threadIdx.x;
  if (i < 512){
    double ang = -2.0*M_PI*(double)i/512.0;
    tw512[i] = make_double2(cos(ang), sin(ang));
  }
  if (i < 1024){
    double ang = 2.0*M_PI*(double)i/1024.0;
    tw1024[i] = make_double2(cos(ang), sin(ang));
  }
  if (i < 512){
    float n  = (float)i - 256.0f;
    float xi = n * (1.0f/(float)G);
    float a  = (float)M_PI * 6.0f * xi;
    float t  = a*a - ALPHA_F*ALPHA_F;
    float z  = sqrtf(fabsf(t));
    float kbft;
    if (t < 0.0f) kbft = sinhf(z) / fmaxf(z, 1e-12f);
    else          kbft = (z < 1e-12f) ? 1.0f : sinf(z)/z;
    kbft *= 6.0f / i0f(ALPHA_F);
    dpod[i] = 1.0f / kbft;
  }
}

// ---------------- KB records per point -------------------------------------
__global__ __launch_bounds__(256) void precompute_kb(const float* __restrict__ ktraj,
    PointRec* __restrict__ rec, float* __restrict__ wdc){
  int k = blockIdx.x*blockDim.x + threadIdx.x;
  if (k >= KPTS) return;
  const float gfac = (float)((double)G/(2.0*M_PI));
  const float inv_i0a = 1.0f / i0f(ALPHA_F);
  PointRec r;
  #pragma unroll
  for (int dim = 0; dim < 2; ++dim){
    float om = ktraj[(size_t)dim*KPTS + k];
    float gx = om * gfac;
    int k0 = (int)floorf(gx);
    #pragma unroll
    for (int j = 0; j < 6; ++j){
      int idx = k0 + (j - 2);
      float d = gx - (float)idx;
      float u = (2.0f*d)*(1.0f/6.0f);
      float t = 1.0f - u*u;
      float w = 0.0f;
      if (t > 0.0f) w = i0f(ALPHA_F * sqrtf(fmaxf(t, 1e-20f))) * inv_i0a;
      if (dim == 0) r.wy[j] = w; else r.wx[j] = w;
    }
    int i0v = (k0 - 2 + 2048) & (G-1);
    if (dim == 0) r.iy0 = i0v; else r.ix0 = i0v;
  }
  r.pad0 = 0; r.pad1 = 0;
  rec[k] = r;
  wdc[k] = 1.0f;
}

// ---------------- tile list build ------------------------------------------
__device__ __forceinline__ int tiles_of(int iy0, int ix0, int* tl){
  int ty0 = iy0>>5, ty1 = ((iy0+5)&(G-1))>>5;
  int tx0 = ix0>>5, tx1 = ((ix0+5)&(G-1))>>5;
  int n = 0;
  tl[n++] = ty0*32+tx0;
  if (tx1!=tx0) tl[n++] = ty0*32+tx1;
  if (ty1!=ty0){
    tl[n++] = ty1*32+tx0;
    if (tx1!=tx0) tl[n++] = ty1*32+tx1;
  }
  return n;
}

__global__ __launch_bounds__(256) void count_tiles(const PointRec* __restrict__ rec,
    int* __restrict__ cnt){
  int k = blockIdx.x*blockDim.x + threadIdx.x;
  if (k >= KPTS) return;
  int tl[4];
  int n = tiles_of(rec[k].iy0, rec[k].ix0, tl);
  for (int i=0;i<n;i++) atomicAdd(&cnt[tl[i]], 1);
}

__global__ __launch_bounds__(1024) void scan_build(const int* __restrict__ cnt,
    int* __restrict__ tileStart, int4* __restrict__ chunkTbl, int* __restrict__ nChunks){
  __shared__ int s[1024];
  int t = threadIdx.x;
  int c = cnt[t];
  s[t] = c; __syncthreads();
  for (int off=1; off<1024; off<<=1){
    int v = (t>=off) ? s[t-off] : 0;
    __syncthreads();
    s[t] += v;
    __syncthreads();
  }
  int excl = s[t] - c;
  tileStart[t] = excl;
  if (t==1023) tileStart[1024] = s[1023];
  int nch = (c + CAP - 1)/CAP;
  __syncthreads();
  s[t] = nch; __syncthreads();
  for (int off=1; off<1024; off<<=1){
    int v = (t>=off) ? s[t-off] : 0;
    __syncthreads();
    s[t] += v;
    __syncthreads();
  }
  int cbase = s[t] - nch;
  for (int i=0;i<nch;i++)
    chunkTbl[cbase+i] = make_int4(t, excl + i*CAP, min(CAP, c - i*CAP), 0);
  if (t==1023) *nChunks = s[1023];
}

__global__ __launch_bounds__(256) void fill_pairs(const PointRec* __restrict__ rec,
    const int* __restrict__ tileStart, int* __restrict__ fill, int* __restrict__ pairs){
  int k = blockIdx.x*blockDim.x + threadIdx.x;
  if (k >= KPTS) return;
  int tl[4];
  int n = tiles_of(rec[k].iy0, rec[k].ix0, tl);
  for (int i=0;i<n;i++){
    int t = tl[i];
    int pos = atomicAdd(&fill[t], 1);
    pairs[tileStart[t] + pos] = k;
  }
}

// ---------------- 512-pt row DFT with fftshifts (f64 accum) ----------------
__global__ __launch_bounds__(256) void rowfft(const float* __restrict__ sino,
    const double2* __restrict__ tw512g, float2* __restrict__ kd){
  __shared__ float   srow[NDET];
  __shared__ double2 tw[NDET];
  int a = blockIdx.x;
  for (int i = threadIdx.x; i < NDET; i += blockDim.x){
    srow[i] = sino[(size_t)a*NDET + i];
    tw[i]   = tw512g[i];
  }
  __syncthreads();
  int k0 = threadIdx.x, k1 = threadIdx.x + 256;
  int kp0 = (k0 + 256) & 511, kp1 = (k1 + 256) & 511;
  double ar0=0, ai0=0, ar1=0, ai1=0;
  for (int n = 0; n < NDET; ++n){
    float s = srow[(n + 256) & 511];
    double2 t0 = tw[(n*kp0) & 511];
    double2 t1 = tw[(n*kp1) & 511];
    ar0 += s*t0.x; ai0 += s*t0.y;
    ar1 += s*t1.x; ai1 += s*t1.y;
  }
  kd[(size_t)a*NDET + k0] = make_float2((float)ar0, (float)ai0);
  kd[(size_t)a*NDET + k1] = make_float2((float)ar1, (float)ai1);
}

// ---------------- owner-cell scatter (gather form): real -------------------
// Thread owns 4 cells (rows cy0+{0,8,16,24}, col cx). Only ONE strided row can
// fall in the 6-row footprint -> single wy LDS read + 4 selects. Batches are
// padded to 256 (zeroed wx columns) so the p-loop has a constant trip count.
__global__ __launch_bounds__(256) void scatter_real_g(
    const int4* __restrict__ chunkTbl, const int* __restrict__ nChunks,
    const int* __restrict__ pairs, const PointRec* __restrict__ rec,
    const float* __restrict__ wdc, float* __restrict__ grid){
  __shared__ float s_wy[8][257];
  __shared__ float s_wx[8][257];
  __shared__ int   s_iy[256], s_ix[256];
  int b = blockIdx.x;
  if (b >= *nChunks) return;
  int4 ch = chunkTbl[b];
  int tyc = (ch.x>>5)<<5, txc = (ch.x&31)<<5;
  int t = threadIdx.x;
  int cx  = txc + (t & 31);
  int cy0 = tyc + (t >> 5);
  // zero pad rows 6,7 once; init index arrays (pad slots read zeroed weights)
  for (int i = t; i < 257; i += 256){
    s_wy[6][i]=0.f; s_wy[7][i]=0.f; s_wx[6][i]=0.f; s_wx[7][i]=0.f;
  }
  s_iy[t] = 0; s_ix[t] = 0;
  float acc0=0.f, acc1=0.f, acc2=0.f, acc3=0.f;
  for (int base = 0; base < ch.z; base += 256){
    int n = min(256, ch.z - base);
    __syncthreads();
    if (t < n){
      int k = pairs[ch.y + base + t];
      PointRec r = rec[k];
      float val = wdc[k];
      #pragma unroll
      for (int j = 0; j < 6; ++j){ s_wy[j][t] = r.wy[j]; s_wx[j][t] = r.wx[j]*val; }
      s_iy[t] = r.iy0; s_ix[t] = r.ix0;
    } else {
      #pragma unroll
      for (int j = 0; j < 6; ++j) s_wx[j][t] = 0.f;   // pad: zero wx kills contribution
    }
    __syncthreads();
    #pragma unroll 4
    for (int p = 0; p < 256; ++p){
      int ix0 = s_ix[p], iy0 = s_iy[p];
      int dx  = (cx - ix0) & (G-1);
      float wxv = s_wx[min(dx,7)][p];
      int dy0 = (cy0 - iy0) & (G-1);
      int dy1 = (dy0 + 8)  & (G-1);
      int dy2 = (dy0 + 16) & (G-1);
      int dy3 = (dy0 + 24) & (G-1);
      int dm  = min(min(dy0,dy1), min(dy2,dy3));
      float wy = s_wy[min(dm,7)][p];        // at most one dy_s can be <8
      float f0 = (dy0 < 8) ? wy : 0.f;
      float f1 = (dy1 < 8) ? wy : 0.f;
      float f2 = (dy2 < 8) ? wy : 0.f;
      float f3 = (dy3 < 8) ? wy : 0.f;
      acc0 = fmaf(f0, wxv, acc0);
      acc1 = fmaf(f1, wxv, acc1);
      acc2 = fmaf(f2, wxv, acc2);
      acc3 = fmaf(f3, wxv, acc3);
    }
  }
  size_t rowb = ((size_t)cy0 << 10) + cx;
  if (acc0 != 0.f) atomicAdd(&grid[rowb],           acc0);
  if (acc1 != 0.f) atomicAdd(&grid[rowb + (8<<10)], acc1);
  if (acc2 != 0.f) atomicAdd(&grid[rowb + (16<<10)],acc2);
  if (acc3 != 0.f) atomicAdd(&grid[rowb + (24<<10)],acc3);
}

// ---------------- owner-cell scatter (gather form): complex ----------------
__global__ __launch_bounds__(256) void scatter_cplx_g(
    const int4* __restrict__ chunkTbl, const int* __restrict__ nChunks,
    const int* __restrict__ pairs, const PointRec* __restrict__ rec,
    const float2* __restrict__ kd, const float* __restrict__ wdc,
    float* __restrict__ gridc){
  __shared__ float s_wy [8][257];
  __shared__ float s_wxr[8][257];
  __shared__ float s_wxi[8][257];
  __shared__ int   s_iy[256], s_ix[256];
  int b = blockIdx.x;
  if (b >= *nChunks) return;
  int4 ch = chunkTbl[b];
  int tyc = (ch.x>>5)<<5, txc = (ch.x&31)<<5;
  int t = threadIdx.x;
  int cx  = txc + (t & 31);
  int cy0 = tyc + (t >> 5);
  for (int i = t; i < 257; i += 256){
    s_wy[6][i]=0.f; s_wy[7][i]=0.f;
    s_wxr[6][i]=0.f; s_wxr[7][i]=0.f;
    s_wxi[6][i]=0.f; s_wxi[7][i]=0.f;
  }
  s_iy[t] = 0; s_ix[t] = 0;
  float ar0=0.f, ar1=0.f, ar2=0.f, ar3=0.f;
  float ai0=0.f, ai1=0.f, ai2=0.f, ai3=0.f;
  for (int base = 0; base < ch.z; base += 256){
    int n = min(256, ch.z - base);
    __syncthreads();
    if (t < n){
      int k = pairs[ch.y + base + t];
      PointRec r = rec[k];
      float2 kv = kd[k];
      float dc = wdc[k];
      float vr = kv.x*dc, vi = kv.y*dc;
      #pragma unroll
      for (int j = 0; j < 6; ++j){
        s_wy [j][t] = r.wy[j];
        s_wxr[j][t] = r.wx[j]*vr;
        s_wxi[j][t] = r.wx[j]*vi;
      }
      s_iy[t] = r.iy0; s_ix[t] = r.ix0;
    } else {
      #pragma unroll
      for (int j = 0; j < 6; ++j){ s_wxr[j][t] = 0.f; s_wxi[j][t] = 0.f; }
    }
    __syncthreads();
    #pragma unroll 4
    for (int p = 0; p < 256; ++p){
      int ix0 = s_ix[p], iy0 = s_iy[p];
      int dx  = (cx - ix0) & (G-1);
      int dxc = min(dx,7);
      float wr = s_wxr[dxc][p];
      float wi = s_wxi[dxc][p];
      int dy0 = (cy0 - iy0) & (G-1);
      int dy1 = (dy0 + 8)  & (G-1);
      int dy2 = (dy0 + 16) & (G-1);
      int dy3 = (dy0 + 24) & (G-1);
      int dm  = min(min(dy0,dy1), min(dy2,dy3));
      float wy = s_wy[min(dm,7)][p];
      float f0 = (dy0 < 8) ? wy : 0.f;
      float f1 = (dy1 < 8) ? wy : 0.f;
      float f2 = (dy2 < 8) ? wy : 0.f;
      float f3 = (dy3 < 8) ? wy : 0.f;
      ar0 = fmaf(f0, wr, ar0);  ai0 = fmaf(f0, wi, ai0);
      ar1 = fmaf(f1, wr, ar1);  ai1 = fmaf(f1, wi, ai1);
      ar2 = fmaf(f2, wr, ar2);  ai2 = fmaf(f2, wi, ai2);
      ar3 = fmaf(f3, wr, ar3);  ai3 = fmaf(f3, wi, ai3);
    }
  }
  size_t cell = ((size_t)cy0 << 10) + cx;
  if (ar0 != 0.f || ai0 != 0.f){ atomicAdd(&gridc[cell*2],            ar0); atomicAdd(&gridc[cell*2+1],            ai0); }
  if (ar1 != 0.f || ai1 != 0.f){ atomicAdd(&gridc[(cell+(8<<10))*2],  ar1); atomicAdd(&gridc[(cell+(8<<10))*2+1],  ai1); }
  if (ar2 != 0.f || ai2 != 0.f){ atomicAdd(&gridc[(cell+(16<<10))*2], ar2); atomicAdd(&gridc[(cell+(16<<10))*2+1], ai2); }
  if (ar3 != 0.f || ai3 != 0.f){ atomicAdd(&gridc[(cell+(24<<10))*2], ar3); atomicAdd(&gridc[(cell+(24<<10))*2+1], ai3); }
}

// ---------------- gather + divide (dcomp) ----------------------------------
__global__ __launch_bounds__(256) void gather_div(const PointRec* __restrict__ rec,
    const float* __restrict__ grid, float* __restrict__ wdc){
  int k = blockIdx.x*blockDim.x + threadIdx.x;
  if (k >= KPTS) return;
  PointRec r = rec[k];
  float s = 0.f;
  #pragma unroll
  for (int j = 0; j < 6; ++j){
    int rowb = ((r.iy0 + j) & (G-1)) << 10;
    float rs = 0.f;
    #pragma unroll
    for (int i = 0; i < 6; ++i)
      rs += grid[rowb + ((r.ix0 + i) & (G-1))] * r.wx[i];
    s += rs * r.wy[j];
  }
  wdc[k] = wdc[k] / fmaxf(fabsf(s), 1e-12f);
}

// ---------------- IFFT pass 1: rows ----------------------------------------
__global__ __launch_bounds__(256) void ifft_rows(const float2* __restrict__ gridc,
    const double2* __restrict__ tw1024g, float2* __restrict__ W1T){
  __shared__ float2  row[G];
  __shared__ double2 tw[G];
  int r = blockIdx.x;
  for (int i = threadIdx.x; i < G; i += blockDim.x){
    row[i] = gridc[(size_t)r*G + i];
    tw[i]  = tw1024g[i];
  }
  __syncthreads();
  int q0 = threadIdx.x, q1 = threadIdx.x + 256;
  int m0 = (q0 + 768) & (G-1), m1 = (q1 + 768) & (G-1);
  double ar0=0, ai0=0, ar1=0, ai1=0;
  for (int c = 0; c < G; ++c){
    float2 v = row[c];
    double2 t0 = tw[(c*m0) & (G-1)];
    double2 t1 = tw[(c*m1) & (G-1)];
    ar0 += v.x*t0.x - v.y*t0.y;  ai0 += v.x*t0.y + v.y*t0.x;
    ar1 += v.x*t1.x - v.y*t1.y;  ai1 += v.x*t1.y + v.y*t1.x;
  }
  W1T[(size_t)q0*G + r] = make_float2((float)ar0, (float)ai0);
  W1T[(size_t)q1*G + r] = make_float2((float)ar1, (float)ai1);
}

// ---------------- IFFT pass 2: cols + deapod + crop ------------------------
__global__ __launch_bounds__(256) void ifft_cols(const float2* __restrict__ W1T,
    const double2* __restrict__ tw1024g, const float* __restrict__ dpod,
    float* __restrict__ out){
  __shared__ float2  col[G];
  __shared__ double2 tw[G];
  int q = blockIdx.x;
  for (int i = threadIdx.x; i < G; i += blockDim.x){
    col[i] = W1T[(size_t)q*G + i];
    tw[i]  = tw1024g[i];
  }
  __syncthreads();
  float dq = dpod[q];
  int p0 = threadIdx.x, p1 = threadIdx.x + 256;
  int m0 = (p0 + 768) & (G-1), m1 = (p1 + 768) & (G-1);
  double ar0=0, ar1=0;
  for (int r = 0; r < G; ++r){
    float2 v = col[r];
    double2 t0 = tw[(r*m0) & (G-1)];
    double2 t1 = tw[(r*m1) & (G-1)];
    ar0 += v.x*t0.x - v.y*t0.y;
    ar1 += v.x*t1.x - v.y*t1.y;
  }
  out[(size_t)p0*WW + q] = (float)ar0 * (1.0f/1024.0f) * dpod[p0] * dq;
  out[(size_t)p1*WW + q] = (float)ar1 * (1.0f/1024.0f) * dpod[p1] * dq;
}

// ---------------------------------------------------------------------------
extern "C" void kernel_launch(void* const* d_in, const int* in_sizes, int n_in,
                              void* d_out, int out_size, void* d_ws, size_t ws_size,
                              hipStream_t stream){
  const float* sino  = (const float*)d_in[0];
  const float* ktraj = (const float*)d_in[1];
  float* out = (float*)d_out;
  char* ws = (char*)d_ws;

  double2*  tw512   = (double2*) (ws + O_TW512);
  double2*  tw1024  = (double2*) (ws + O_TW1024);
  float*    dpod    = (float*)   (ws + O_DPOD);
  int*      cnt     = (int*)     (ws + O_CNT);
  int*      fill    = (int*)     (ws + O_FILL);
  int*      tstart  = (int*)     (ws + O_START);
  int*      nch     = (int*)     (ws + O_NCH);
  int4*     chunkT  = (int4*)    (ws + O_CHUNK);
  PointRec* rec     = (PointRec*)(ws + O_REC);
  int*      pairs   = (int*)     (ws + O_PAIRS);
  float*    wdc     = (float*)   (ws + O_WDC);
  float2*   kd      = (float2*)  (ws + O_KD);
  float*    gridR   = (float*)   (ws + O_GR);
  float2*   gridC   = (float2*)  (ws + O_GC);
  float2*   W1T     = (float2*)  (ws + O_REC);   // reuse record space (dead by then)

  const int PB = (KPTS + 255)/256;   // 1440

  gen_tables<<<4, 256, 0, stream>>>(tw512, tw1024, dpod);
  precompute_kb<<<PB, 256, 0, stream>>>(ktraj, rec, wdc);
  rowfft<<<NANG, 256, 0, stream>>>(sino, tw512, kd);

  // build tile lists (once per call; reused by all 11 scatters)
  hipMemsetAsync(cnt, 0, 8192, stream);          // cnt + fill (adjacent)
  count_tiles<<<PB, 256, 0, stream>>>(rec, cnt);
  scan_build<<<1, 1024, 0, stream>>>(cnt, tstart, chunkT, nch);
  fill_pairs<<<PB, 256, 0, stream>>>(rec, tstart, fill, pairs);

  for (int it = 0; it < NITER_DCOMP; ++it){
    hipMemsetAsync(gridR, 0, (size_t)GG*sizeof(float), stream);
    scatter_real_g<<<NSCATTER_BLOCKS, 256, 0, stream>>>(chunkT, nch, pairs, rec, wdc, gridR);
    gather_div<<<PB, 256, 0, stream>>>(rec, gridR, wdc);
  }

  hipMemsetAsync(gridC, 0, (size_t)GG*2*sizeof(float), stream);
  scatter_cplx_g<<<NSCATTER_BLOCKS, 256, 0, stream>>>(chunkT, nch, pairs, rec, kd, wdc, (float*)gridC);

  ifft_rows<<<G, 256, 0, stream>>>(gridC, tw1024, W1T);
  ifft_cols<<<WW, 256, 0, stream>>>(W1T, tw1024, dpod, out);
}

// Round 11
// 2317.075 us; speedup vs baseline: 2.3618x; 1.2797x over previous
//
#include <hip/hip_runtime.h>
#include <math.h>

#define NANG 720
#define NDET 512
#define KPTS (NANG*NDET)        // 368640
#define G 1024
#define GG (G*G)
#define ALPHA_F 14.04f
#define NITER_DCOMP 10
#define WW 512

#define CAP 1024                 // max points per scatter chunk
#define PAIR_CAP 1474624         // >= hard worst case 4*KPTS = 1474560
#define NSCATTER_BLOCKS 2464     // >= 1024 + PAIR_CAP/CAP = 2464

#define NB_BIN 288               // blocks for binning kernels
#define PPB ((KPTS + NB_BIN - 1)/NB_BIN)   // 1280 points per block

// ---------------- workspace layout (byte offsets) --------------------------
#define O_TW512   0UL            // 512 double2
#define O_TW1024  8192UL         // 1024 double2
#define O_DPOD    24576UL        // 512 f32
#define O_CNT     32768UL        // 1024 int
#define O_FILL    36864UL        // 1024 int
#define O_START   40960UL        // 1025 int
#define O_NCH     46080UL        // 1 int
#define O_CHUNK   49152UL        // 4096 int4 (64KB; need <= 2464)
#define O_REC     131072UL       // KPTS * 64B = 23.6MB   (reused as W1T later)
#define O_PAIRS   (O_REC   + (size_t)KPTS*64)       // PAIR_CAP int = 5.9MB
#define O_WDC     (O_PAIRS + (size_t)PAIR_CAP*4)    // K f32
#define O_KD      (O_WDC   + (size_t)KPTS*4)        // K float2
#define O_GR      (O_KD    + (size_t)KPTS*8)        // GG f32
#define O_GC      (O_GR    + (size_t)GG*4)          // GG float2
// end ~44.5MB

struct __align__(16) PointRec {
  float wy[6];
  float wx[6];
  int   iy0, ix0;
  int   pad0, pad1;   // 64B total
};

// ---------------- modified Bessel I0 (Abramowitz-Stegun) -------------------
__device__ __forceinline__ float i0f(float x){
  float ax = fabsf(x);
  if (ax < 3.75f){
    float t = ax*(1.0f/3.75f); t *= t;
    return 1.0f + t*(3.5156229f + t*(3.0899424f + t*(1.2067492f +
           t*(0.2659732f + t*(0.0360768f + t*0.0045813f)))));
  } else {
    float t = 3.75f/ax;
    float p = 0.39894228f + t*(0.01328592f + t*(0.00225319f + t*(-0.00157565f +
              t*(0.00916281f + t*(-0.02057706f + t*(0.02635537f +
              t*(-0.01647633f + t*0.00392377f)))))));
    return expf(ax)*rsqrtf(ax)*p;
  }
}

// ---------------- tables ---------------------------------------------------
__global__ __launch_bounds__(256) void gen_tables(double2* tw512, double2* tw1024, float* dpod){
  int i = blockIdx.x*blockDim.x + threadIdx.x;
  if (i < 512){
    double ang = -2.0*M_PI*(double)i/512.0;
    tw512[i] = make_double2(cos(ang), sin(ang));
  }
  if (i < 1024){
    double ang = 2.0*M_PI*(double)i/1024.0;
    tw1024[i] = make_double2(cos(ang), sin(ang));
  }
  if (i < 512){
    float n  = (float)i - 256.0f;
    float xi = n * (1.0f/(float)G);
    float a  = (float)M_PI * 6.0f * xi;
    float t  = a*a - ALPHA_F*ALPHA_F;
    float z  = sqrtf(fabsf(t));
    float kbft;
    if (t < 0.0f) kbft = sinhf(z) / fmaxf(z, 1e-12f);
    else          kbft = (z < 1e-12f) ? 1.0f : sinf(z)/z;
    kbft *= 6.0f / i0f(ALPHA_F);
    dpod[i] = 1.0f / kbft;
  }
}

// ---------------- KB records per point -------------------------------------
__global__ __launch_bounds__(256) void precompute_kb(const float* __restrict__ ktraj,
    PointRec* __restrict__ rec, float* __restrict__ wdc){
  int k = blockIdx.x*blockDim.x + threadIdx.x;
  if (k >= KPTS) return;
  const float gfac = (float)((double)G/(2.0*M_PI));
  const float inv_i0a = 1.0f / i0f(ALPHA_F);
  PointRec r;
  #pragma unroll
  for (int dim = 0; dim < 2; ++dim){
    float om = ktraj[(size_t)dim*KPTS + k];
    float gx = om * gfac;
    int k0 = (int)floorf(gx);
    #pragma unroll
    for (int j = 0; j < 6; ++j){
      int idx = k0 + (j - 2);
      float d = gx - (float)idx;
      float u = (2.0f*d)*(1.0f/6.0f);
      float t = 1.0f - u*u;
      float w = 0.0f;
      if (t > 0.0f) w = i0f(ALPHA_F * sqrtf(fmaxf(t, 1e-20f))) * inv_i0a;
      if (dim == 0) r.wy[j] = w; else r.wx[j] = w;
    }
    int i0v = (k0 - 2 + 2048) & (G-1);
    if (dim == 0) r.iy0 = i0v; else r.ix0 = i0v;
  }
  r.pad0 = 0; r.pad1 = 0;
  rec[k] = r;
  wdc[k] = 1.0f;
}

// ---------------- tile list build ------------------------------------------
__device__ __forceinline__ int tiles_of(int iy0, int ix0, int* tl){
  int ty0 = iy0>>5, ty1 = ((iy0+5)&(G-1))>>5;
  int tx0 = ix0>>5, tx1 = ((ix0+5)&(G-1))>>5;
  int n = 0;
  tl[n++] = ty0*32+tx0;
  if (tx1!=tx0) tl[n++] = ty0*32+tx1;
  if (ty1!=ty0){
    tl[n++] = ty1*32+tx0;
    if (tx1!=tx0) tl[n++] = ty1*32+tx1;
  }
  return n;
}

// LDS-privatized tile count: per-block histogram, one flush atomic per bin.
__global__ __launch_bounds__(256) void count_tiles_p(const PointRec* __restrict__ rec,
    int* __restrict__ cnt){
  __shared__ int h[1024];
  int t = threadIdx.x;
  for (int i = t; i < 1024; i += 256) h[i] = 0;
  __syncthreads();
  int k0 = blockIdx.x * PPB;
  int k1 = min(k0 + PPB, KPTS);
  for (int k = k0 + t; k < k1; k += 256){
    int tl[4];
    int n = tiles_of(rec[k].iy0, rec[k].ix0, tl);
    for (int i=0;i<n;i++) atomicAdd(&h[tl[i]], 1);
  }
  __syncthreads();
  for (int i = t; i < 1024; i += 256)
    if (h[i]) atomicAdd(&cnt[i], h[i]);
}

__global__ __launch_bounds__(1024) void scan_build(const int* __restrict__ cnt,
    int* __restrict__ tileStart, int4* __restrict__ chunkTbl, int* __restrict__ nChunks){
  __shared__ int s[1024];
  int t = threadIdx.x;
  int c = cnt[t];
  s[t] = c; __syncthreads();
  for (int off=1; off<1024; off<<=1){
    int v = (t>=off) ? s[t-off] : 0;
    __syncthreads();
    s[t] += v;
    __syncthreads();
  }
  int excl = s[t] - c;
  tileStart[t] = excl;
  if (t==1023) tileStart[1024] = s[1023];
  int nch = (c + CAP - 1)/CAP;
  __syncthreads();
  s[t] = nch; __syncthreads();
  for (int off=1; off<1024; off<<=1){
    int v = (t>=off) ? s[t-off] : 0;
    __syncthreads();
    s[t] += v;
    __syncthreads();
  }
  int cbase = s[t] - nch;
  for (int i=0;i<nch;i++)
    chunkTbl[cbase+i] = make_int4(t, excl + i*CAP, min(CAP, c - i*CAP), 0);
  if (t==1023) *nChunks = s[1023];
}

// Blocked fill: per-block LDS count -> reserve global ranges -> place points.
__global__ __launch_bounds__(256) void fill_pairs_b(const PointRec* __restrict__ rec,
    const int* __restrict__ tileStart, int* __restrict__ fill, int* __restrict__ pairs){
  __shared__ int lcnt[1024];
  __shared__ int lbase[1024];
  int t = threadIdx.x;
  for (int i = t; i < 1024; i += 256) lcnt[i] = 0;
  __syncthreads();
  int k0 = blockIdx.x * PPB;
  int k1 = min(k0 + PPB, KPTS);
  // phase 1: local counts
  for (int k = k0 + t; k < k1; k += 256){
    int tl[4];
    int n = tiles_of(rec[k].iy0, rec[k].ix0, tl);
    for (int i=0;i<n;i++) atomicAdd(&lcnt[tl[i]], 1);
  }
  __syncthreads();
  // phase 2: reserve a contiguous range per nonzero bin; reset local counter
  for (int i = t; i < 1024; i += 256){
    int c = lcnt[i];
    if (c) lbase[i] = atomicAdd(&fill[i], c);
    lcnt[i] = 0;
  }
  __syncthreads();
  // phase 3: place points at block-local positions within the reserved range
  for (int k = k0 + t; k < k1; k += 256){
    int tl[4];
    int n = tiles_of(rec[k].iy0, rec[k].ix0, tl);
    for (int i=0;i<n;i++){
      int tt = tl[i];
      int pos = atomicAdd(&lcnt[tt], 1);
      pairs[tileStart[tt] + lbase[tt] + pos] = k;
    }
  }
}

// ---------------- 512-pt row DFT with fftshifts (f64 accum) ----------------
__global__ __launch_bounds__(256) void rowfft(const float* __restrict__ sino,
    const double2* __restrict__ tw512g, float2* __restrict__ kd){
  __shared__ float   srow[NDET];
  __shared__ double2 tw[NDET];
  int a = blockIdx.x;
  for (int i = threadIdx.x; i < NDET; i += blockDim.x){
    srow[i] = sino[(size_t)a*NDET + i];
    tw[i]   = tw512g[i];
  }
  __syncthreads();
  int k0 = threadIdx.x, k1 = threadIdx.x + 256;
  int kp0 = (k0 + 256) & 511, kp1 = (k1 + 256) & 511;
  double ar0=0, ai0=0, ar1=0, ai1=0;
  for (int n = 0; n < NDET; ++n){
    float s = srow[(n + 256) & 511];
    double2 t0 = tw[(n*kp0) & 511];
    double2 t1 = tw[(n*kp1) & 511];
    ar0 += s*t0.x; ai0 += s*t0.y;
    ar1 += s*t1.x; ai1 += s*t1.y;
  }
  kd[(size_t)a*NDET + k0] = make_float2((float)ar0, (float)ai0);
  kd[(size_t)a*NDET + k1] = make_float2((float)ar1, (float)ai1);
}

// ---------------- owner-cell scatter (gather form): real -------------------
__global__ __launch_bounds__(256) void scatter_real_g(
    const int4* __restrict__ chunkTbl, const int* __restrict__ nChunks,
    const int* __restrict__ pairs, const PointRec* __restrict__ rec,
    const float* __restrict__ wdc, float* __restrict__ grid){
  __shared__ float s_wy[8][257];
  __shared__ float s_wx[8][257];
  __shared__ int   s_iy[256], s_ix[256];
  int b = blockIdx.x;
  if (b >= *nChunks) return;
  int4 ch = chunkTbl[b];
  int tyc = (ch.x>>5)<<5, txc = (ch.x&31)<<5;
  int t = threadIdx.x;
  int cx  = txc + (t & 31);
  int cy0 = tyc + (t >> 5);
  for (int i = t; i < 257; i += 256){
    s_wy[6][i]=0.f; s_wy[7][i]=0.f; s_wx[6][i]=0.f; s_wx[7][i]=0.f;
  }
  s_iy[t] = 0; s_ix[t] = 0;
  float acc0=0.f, acc1=0.f, acc2=0.f, acc3=0.f;
  for (int base = 0; base < ch.z; base += 256){
    int n = min(256, ch.z - base);
    __syncthreads();
    if (t < n){
      int k = pairs[ch.y + base + t];
      PointRec r = rec[k];
      float val = wdc[k];
      #pragma unroll
      for (int j = 0; j < 6; ++j){ s_wy[j][t] = r.wy[j]; s_wx[j][t] = r.wx[j]*val; }
      s_iy[t] = r.iy0; s_ix[t] = r.ix0;
    } else {
      #pragma unroll
      for (int j = 0; j < 6; ++j) s_wx[j][t] = 0.f;
    }
    __syncthreads();
    #pragma unroll 4
    for (int p = 0; p < 256; ++p){
      int ix0 = s_ix[p], iy0 = s_iy[p];
      int dx  = (cx - ix0) & (G-1);
      float wxv = s_wx[min(dx,7)][p];
      int dy0 = (cy0 - iy0) & (G-1);
      int dy1 = (dy0 + 8)  & (G-1);
      int dy2 = (dy0 + 16) & (G-1);
      int dy3 = (dy0 + 24) & (G-1);
      int dm  = min(min(dy0,dy1), min(dy2,dy3));
      float wy = s_wy[min(dm,7)][p];
      float f0 = (dy0 < 8) ? wy : 0.f;
      float f1 = (dy1 < 8) ? wy : 0.f;
      float f2 = (dy2 < 8) ? wy : 0.f;
      float f3 = (dy3 < 8) ? wy : 0.f;
      acc0 = fmaf(f0, wxv, acc0);
      acc1 = fmaf(f1, wxv, acc1);
      acc2 = fmaf(f2, wxv, acc2);
      acc3 = fmaf(f3, wxv, acc3);
    }
  }
  size_t rowb = ((size_t)cy0 << 10) + cx;
  if (acc0 != 0.f) atomicAdd(&grid[rowb],           acc0);
  if (acc1 != 0.f) atomicAdd(&grid[rowb + (8<<10)], acc1);
  if (acc2 != 0.f) atomicAdd(&grid[rowb + (16<<10)],acc2);
  if (acc3 != 0.f) atomicAdd(&grid[rowb + (24<<10)],acc3);
}

// ---------------- owner-cell scatter (gather form): complex ----------------
__global__ __launch_bounds__(256) void scatter_cplx_g(
    const int4* __restrict__ chunkTbl, const int* __restrict__ nChunks,
    const int* __restrict__ pairs, const PointRec* __restrict__ rec,
    const float2* __restrict__ kd, const float* __restrict__ wdc,
    float* __restrict__ gridc){
  __shared__ float s_wy [8][257];
  __shared__ float s_wxr[8][257];
  __shared__ float s_wxi[8][257];
  __shared__ int   s_iy[256], s_ix[256];
  int b = blockIdx.x;
  if (b >= *nChunks) return;
  int4 ch = chunkTbl[b];
  int tyc = (ch.x>>5)<<5, txc = (ch.x&31)<<5;
  int t = threadIdx.x;
  int cx  = txc + (t & 31);
  int cy0 = tyc + (t >> 5);
  for (int i = t; i < 257; i += 256){
    s_wy[6][i]=0.f; s_wy[7][i]=0.f;
    s_wxr[6][i]=0.f; s_wxr[7][i]=0.f;
    s_wxi[6][i]=0.f; s_wxi[7][i]=0.f;
  }
  s_iy[t] = 0; s_ix[t] = 0;
  float ar0=0.f, ar1=0.f, ar2=0.f, ar3=0.f;
  float ai0=0.f, ai1=0.f, ai2=0.f, ai3=0.f;
  for (int base = 0; base < ch.z; base += 256){
    int n = min(256, ch.z - base);
    __syncthreads();
    if (t < n){
      int k = pairs[ch.y + base + t];
      PointRec r = rec[k];
      float2 kv = kd[k];
      float dc = wdc[k];
      float vr = kv.x*dc, vi = kv.y*dc;
      #pragma unroll
      for (int j = 0; j < 6; ++j){
        s_wy [j][t] = r.wy[j];
        s_wxr[j][t] = r.wx[j]*vr;
        s_wxi[j][t] = r.wx[j]*vi;
      }
      s_iy[t] = r.iy0; s_ix[t] = r.ix0;
    } else {
      #pragma unroll
      for (int j = 0; j < 6; ++j){ s_wxr[j][t] = 0.f; s_wxi[j][t] = 0.f; }
    }
    __syncthreads();
    #pragma unroll 4
    for (int p = 0; p < 256; ++p){
      int ix0 = s_ix[p], iy0 = s_iy[p];
      int dx  = (cx - ix0) & (G-1);
      int dxc = min(dx,7);
      float wr = s_wxr[dxc][p];
      float wi = s_wxi[dxc][p];
      int dy0 = (cy0 - iy0) & (G-1);
      int dy1 = (dy0 + 8)  & (G-1);
      int dy2 = (dy0 + 16) & (G-1);
      int dy3 = (dy0 + 24) & (G-1);
      int dm  = min(min(dy0,dy1), min(dy2,dy3));
      float wy = s_wy[min(dm,7)][p];
      float f0 = (dy0 < 8) ? wy : 0.f;
      float f1 = (dy1 < 8) ? wy : 0.f;
      float f2 = (dy2 < 8) ? wy : 0.f;
      float f3 = (dy3 < 8) ? wy : 0.f;
      ar0 = fmaf(f0, wr, ar0);  ai0 = fmaf(f0, wi, ai0);
      ar1 = fmaf(f1, wr, ar1);  ai1 = fmaf(f1, wi, ai1);
      ar2 = fmaf(f2, wr, ar2);  ai2 = fmaf(f2, wi, ai2);
      ar3 = fmaf(f3, wr, ar3);  ai3 = fmaf(f3, wi, ai3);
    }
  }
  size_t cell = ((size_t)cy0 << 10) + cx;
  if (ar0 != 0.f || ai0 != 0.f){ atomicAdd(&gridc[cell*2],            ar0); atomicAdd(&gridc[cell*2+1],            ai0); }
  if (ar1 != 0.f || ai1 != 0.f){ atomicAdd(&gridc[(cell+(8<<10))*2],  ar1); atomicAdd(&gridc[(cell+(8<<10))*2+1],  ai1); }
  if (ar2 != 0.f || ai2 != 0.f){ atomicAdd(&gridc[(cell+(16<<10))*2], ar2); atomicAdd(&gridc[(cell+(16<<10))*2+1], ai2); }
  if (ar3 != 0.f || ai3 != 0.f){ atomicAdd(&gridc[(cell+(24<<10))*2], ar3); atomicAdd(&gridc[(cell+(24<<10))*2+1], ai3); }
}

// ---------------- gather + divide (dcomp) ----------------------------------
__global__ __launch_bounds__(256) void gather_div(const PointRec* __restrict__ rec,
    const float* __restrict__ grid, float* __restrict__ wdc){
  int k = blockIdx.x*blockDim.x + threadIdx.x;
  if (k >= KPTS) return;
  PointRec r = rec[k];
  float s = 0.f;
  #pragma unroll
  for (int j = 0; j < 6; ++j){
    int rowb = ((r.iy0 + j) & (G-1)) << 10;
    float rs = 0.f;
    #pragma unroll
    for (int i = 0; i < 6; ++i)
      rs += grid[rowb + ((r.ix0 + i) & (G-1))] * r.wx[i];
    s += rs * r.wy[j];
  }
  wdc[k] = wdc[k] / fmaxf(fabsf(s), 1e-12f);
}

// ---------------- IFFT pass 1: rows ----------------------------------------
__global__ __launch_bounds__(256) void ifft_rows(const float2* __restrict__ gridc,
    const double2* __restrict__ tw1024g, float2* __restrict__ W1T){
  __shared__ float2  row[G];
  __shared__ double2 tw[G];
  int r = blockIdx.x;
  for (int i = threadIdx.x; i < G; i += blockDim.x){
    row[i] = gridc[(size_t)r*G + i];
    tw[i]  = tw1024g[i];
  }
  __syncthreads();
  int q0 = threadIdx.x, q1 = threadIdx.x + 256;
  int m0 = (q0 + 768) & (G-1), m1 = (q1 + 768) & (G-1);
  double ar0=0, ai0=0, ar1=0, ai1=0;
  for (int c = 0; c < G; ++c){
    float2 v = row[c];
    double2 t0 = tw[(c*m0) & (G-1)];
    double2 t1 = tw[(c*m1) & (G-1)];
    ar0 += v.x*t0.x - v.y*t0.y;  ai0 += v.x*t0.y + v.y*t0.x;
    ar1 += v.x*t1.x - v.y*t1.y;  ai1 += v.x*t1.y + v.y*t1.x;
  }
  W1T[(size_t)q0*G + r] = make_float2((float)ar0, (float)ai0);
  W1T[(size_t)q1*G + r] = make_float2((float)ar1, (float)ai1);
}

// ---------------- IFFT pass 2: cols + deapod + crop ------------------------
__global__ __launch_bounds__(256) void ifft_cols(const float2* __restrict__ W1T,
    const double2* __restrict__ tw1024g, const float* __restrict__ dpod,
    float* __restrict__ out){
  __shared__ float2  col[G];
  __shared__ double2 tw[G];
  int q = blockIdx.x;
  for (int i = threadIdx.x; i < G; i += blockDim.x){
    col[i] = W1T[(size_t)q*G + i];
    tw[i]  = tw1024g[i];
  }
  __syncthreads();
  float dq = dpod[q];
  int p0 = threadIdx.x, p1 = threadIdx.x + 256;
  int m0 = (p0 + 768) & (G-1), m1 = (p1 + 768) & (G-1);
  double ar0=0, ar1=0;
  for (int r = 0; r < G; ++r){
    float2 v = col[r];
    double2 t0 = tw[(r*m0) & (G-1)];
    double2 t1 = tw[(r*m1) & (G-1)];
    ar0 += v.x*t0.x - v.y*t0.y;
    ar1 += v.x*t1.x - v.y*t1.y;
  }
  out[(size_t)p0*WW + q] = (float)ar0 * (1.0f/1024.0f) * dpod[p0] * dq;
  out[(size_t)p1*WW + q] = (float)ar1 * (1.0f/1024.0f) * dpod[p1] * dq;
}

// ---------------------------------------------------------------------------
extern "C" void kernel_launch(void* const* d_in, const int* in_sizes, int n_in,
                              void* d_out, int out_size, void* d_ws, size_t ws_size,
                              hipStream_t stream){
  const float* sino  = (const float*)d_in[0];
  const float* ktraj = (const float*)d_in[1];
  float* out = (float*)d_out;
  char* ws = (char*)d_ws;

  double2*  tw512   = (double2*) (ws + O_TW512);
  double2*  tw1024  = (double2*) (ws + O_TW1024);
  float*    dpod    = (float*)   (ws + O_DPOD);
  int*      cnt     = (int*)     (ws + O_CNT);
  int*      fill    = (int*)     (ws + O_FILL);
  int*      tstart  = (int*)     (ws + O_START);
  int*      nch     = (int*)     (ws + O_NCH);
  int4*     chunkT  = (int4*)    (ws + O_CHUNK);
  PointRec* rec     = (PointRec*)(ws + O_REC);
  int*      pairs   = (int*)     (ws + O_PAIRS);
  float*    wdc     = (float*)   (ws + O_WDC);
  float2*   kd      = (float2*)  (ws + O_KD);
  float*    gridR   = (float*)   (ws + O_GR);
  float2*   gridC   = (float2*)  (ws + O_GC);
  float2*   W1T     = (float2*)  (ws + O_REC);   // reuse record space (dead by then)

  const int PB = (KPTS + 255)/256;   // 1440

  gen_tables<<<4, 256, 0, stream>>>(tw512, tw1024, dpod);
  precompute_kb<<<PB, 256, 0, stream>>>(ktraj, rec, wdc);
  rowfft<<<NANG, 256, 0, stream>>>(sino, tw512, kd);

  // build tile lists (once per call; reused by all 11 scatters)
  hipMemsetAsync(cnt, 0, 8192, stream);          // cnt + fill (adjacent)
  count_tiles_p<<<NB_BIN, 256, 0, stream>>>(rec, cnt);
  scan_build<<<1, 1024, 0, stream>>>(cnt, tstart, chunkT, nch);
  fill_pairs_b<<<NB_BIN, 256, 0, stream>>>(rec, tstart, fill, pairs);

  for (int it = 0; it < NITER_DCOMP; ++it){
    hipMemsetAsync(gridR, 0, (size_t)GG*sizeof(float), stream);
    scatter_real_g<<<NSCATTER_BLOCKS, 256, 0, stream>>>(chunkT, nch, pairs, rec, wdc, gridR);
    gather_div<<<PB, 256, 0, stream>>>(rec, gridR, wdc);
  }

  hipMemsetAsync(gridC, 0, (size_t)GG*2*sizeof(float), stream);
  scatter_cplx_g<<<NSCATTER_BLOCKS, 256, 0, stream>>>(chunkT, nch, pairs, rec, kd, wdc, (float*)gridC);

  ifft_rows<<<G, 256, 0, stream>>>(gridC, tw1024, W1T);
  ifft_cols<<<WW, 256, 0, stream>>>(W1T, tw1024, dpod, out);
}